// Round 3
// baseline (521.397 us; speedup 1.0000x reference)
//
#include <hip/hip_runtime.h>
#include <hip/hip_bf16.h>

using bf16 = __hip_bfloat16;
using bf16x8 = __attribute__((ext_vector_type(8))) short;
using f32x4 = __attribute__((ext_vector_type(4))) float;

#define MFMA16(a, b, c) __builtin_amdgcn_mfma_f32_16x16x32_bf16((a), (b), (c), 0, 0, 0)

static __device__ __forceinline__ float bf2f(bf16 v) { return __bfloat162float(v); }
static __device__ __forceinline__ bf16 f2bf(float v) { return __float2bfloat16(v); }

typedef const __attribute__((address_space(1))) void* gptr_t;
typedef __attribute__((address_space(3))) void* lptr_t;
static __device__ __forceinline__ void gload16(const void* g, void* l) {
    __builtin_amdgcn_global_load_lds((gptr_t)g, (lptr_t)l, 16, 0, 0);
}

// ---------------------------------------------------------------------------
// Weight transpose + f32->bf16: W[K=2048][N] -> Wt[N][2048]
// ---------------------------------------------------------------------------
__global__ __launch_bounds__(256) void transpose_w(const float* __restrict__ W,
                                                   bf16* __restrict__ Wt, int N) {
    const int n0 = blockIdx.x * 32;
    const int k0 = blockIdx.y * 32;
    __shared__ __align__(16) float tile[32][36];
    const int t = threadIdx.x;
    {
        const int i = t >> 3, j4 = (t & 7) * 4;
        *reinterpret_cast<float4*>(&tile[i][j4]) =
            *reinterpret_cast<const float4*>(&W[(size_t)(k0 + i) * N + n0 + j4]);
    }
    __syncthreads();
    {
        const int j = t >> 3, i4 = (t & 7) * 4;
        alignas(8) bf16 v4[4];
#pragma unroll
        for (int u = 0; u < 4; ++u) v4[u] = f2bf(tile[i4 + u][j]);
        *reinterpret_cast<uint2*>(&Wt[(size_t)(n0 + j) * 2048 + k0 + i4]) =
            *reinterpret_cast<uint2*>(v4);
    }
}

// ---------------------------------------------------------------------------
// x f32 -> bf16 (vectorized 8/thread)
// ---------------------------------------------------------------------------
__global__ __launch_bounds__(256) void convert_x(const float* __restrict__ X,
                                                 bf16* __restrict__ Xb, int n8) {
    int idx = blockIdx.x * 256 + threadIdx.x;
    if (idx >= n8) return;
    const float4 a = reinterpret_cast<const float4*>(X)[idx * 2];
    const float4 c = reinterpret_cast<const float4*>(X)[idx * 2 + 1];
    alignas(16) bf16 v8[8];
    v8[0] = f2bf(a.x); v8[1] = f2bf(a.y); v8[2] = f2bf(a.z); v8[3] = f2bf(a.w);
    v8[4] = f2bf(c.x); v8[5] = f2bf(c.y); v8[6] = f2bf(c.z); v8[7] = f2bf(c.w);
    reinterpret_cast<int4*>(Xb)[idx] = *reinterpret_cast<int4*>(v8);
}

// ---------------------------------------------------------------------------
// mask -> additive float bias: maddf[i] = -10000 * (1 - mask[i])
// ---------------------------------------------------------------------------
__global__ __launch_bounds__(256) void mask_to_f(const int* __restrict__ m,
                                                 float* __restrict__ f, int n) {
    int i = blockIdx.x * 256 + threadIdx.x;
    if (i < n) f[i] = -10000.0f * (float)(1 - m[i]);
}

// ---------------------------------------------------------------------------
// GEMM (m97 structure): C[M][N] = A[M][K](bf16) @ Bt[N][K](bf16)^T, f32 acc.
// ---------------------------------------------------------------------------
template <typename OUT_T>
__global__ __launch_bounds__(256) void gemm_bt(const bf16* __restrict__ A,
                                               const bf16* __restrict__ Bt,
                                               OUT_T* __restrict__ C,
                                               int M, int N, int K) {
    __shared__ __align__(16) bf16 As[128 * 32];
    __shared__ __align__(16) bf16 Bs[128 * 32];
    const int t = threadIdx.x;
    const int lane = t & 63;
    const int wave = t >> 6;
    const int m0 = blockIdx.y * 128;
    const int n0 = blockIdx.x * 128;
    const int wr = (wave >> 1) * 64;
    const int wc = (wave & 1) * 64;
    const int fr = lane & 15;
    const int fg = lane >> 4;
    f32x4 acc[4][4] = {};
    const int g0 = wave * 2 * 64 + lane;
    const int g1 = g0 + 64;
    const int r0 = g0 >> 2, c0 = (g0 & 3) * 8;
    const int r1 = g1 >> 2, c1 = (g1 & 3) * 8;
    for (int k0 = 0; k0 < K; k0 += 32) {
        __syncthreads();
        gload16(&A[(size_t)(m0 + r0) * K + k0 + c0], &As[(size_t)g0 * 8 - lane * 8]);
        gload16(&A[(size_t)(m0 + r1) * K + k0 + c1], &As[(size_t)g1 * 8 - lane * 8]);
        gload16(&Bt[(size_t)(n0 + r0) * K + k0 + c0], &Bs[(size_t)g0 * 8 - lane * 8]);
        gload16(&Bt[(size_t)(n0 + r1) * K + k0 + c1], &Bs[(size_t)g1 * 8 - lane * 8]);
        __syncthreads();
        bf16x8 af[4], bfv[4];
#pragma unroll
        for (int m = 0; m < 4; ++m)
            af[m] = *reinterpret_cast<const bf16x8*>(&As[(wr + m * 16 + fr) * 32 + fg * 8]);
#pragma unroll
        for (int n = 0; n < 4; ++n)
            bfv[n] = *reinterpret_cast<const bf16x8*>(&Bs[(wc + n * 16 + fr) * 32 + fg * 8]);
#pragma unroll
        for (int m = 0; m < 4; ++m)
#pragma unroll
            for (int n = 0; n < 4; ++n)
                acc[m][n] = MFMA16(af[m], bfv[n], acc[m][n]);
    }
#pragma unroll
    for (int m = 0; m < 4; ++m) {
#pragma unroll
        for (int r = 0; r < 4; ++r) {
            const int grow = m0 + wr + m * 16 + fg * 4 + r;
#pragma unroll
            for (int n = 0; n < 4; ++n) {
                const int gcol = n0 + wc + n * 16 + fr;
                const float v = acc[m][n][r];
                if constexpr (sizeof(OUT_T) == 2)
                    C[(size_t)grow * N + gcol] = f2bf(v);
                else
                    C[(size_t)grow * N + gcol] = v;
            }
        }
    }
}

// ---------------------------------------------------------------------------
// RoPE + QK-RMS. qkv[4096][3072] bf16 row-major (q | k | v).
// ---------------------------------------------------------------------------
__global__ __launch_bounds__(256) void rope_rms(const bf16* __restrict__ qkv,
                                                const float* __restrict__ cosb,
                                                const float* __restrict__ sinb,
                                                bf16* __restrict__ Qo,
                                                bf16* __restrict__ Ko) {
    const int row = blockIdx.x;  // b*2048 + l
    const int b = row >> 11, l = row & 2047;
    const int wave = threadIdx.x >> 6, lane = threadIdx.x & 63;
    const bf16* src = qkv + (size_t)row * 3072;
#pragma unroll
    for (int i = 0; i < 4; ++i) {
        const int hh = wave * 4 + i;
        float x1 = bf2f(src[hh * 128 + lane]);
        float x2 = bf2f(src[hh * 128 + 64 + lane]);
        size_t cs = ((size_t)row * 16 + hh) * 128 + lane;
        float c = cosb[cs], sn = sinb[cs];
        float o1 = x1 * c - x2 * sn;
        float o2 = x2 * c + x1 * sn;
        float ss = o1 * o1 + o2 * o2;
#pragma unroll
        for (int off = 32; off >= 1; off >>= 1) ss += __shfl_xor(ss, off);
        float scf = rsqrtf(ss * (1.0f / 128.0f) + 1e-6f);
        bf16* dst = Qo + ((size_t)(b * 16 + hh) * 2048 + l) * 128;
        dst[lane] = f2bf(o1 * scf);
        dst[64 + lane] = f2bf(o2 * scf);
    }
    {
        const int hv = wave;
        float x1 = bf2f(src[2048 + hv * 128 + lane]);
        float x2 = bf2f(src[2048 + hv * 128 + 64 + lane]);
        size_t cs = ((size_t)row * 16 + hv) * 128 + lane;
        float c = cosb[cs], sn = sinb[cs];
        float o1 = x1 * c - x2 * sn;
        float o2 = x2 * c + x1 * sn;
        float ss = o1 * o1 + o2 * o2;
#pragma unroll
        for (int off = 32; off >= 1; off >>= 1) ss += __shfl_xor(ss, off);
        float scf = rsqrtf(ss * (1.0f / 128.0f) + 1e-6f);
        bf16* dst = Ko + ((size_t)(b * 4 + hv) * 2048 + l) * 128;
        dst[lane] = f2bf(o1 * scf);
        dst[64 + lane] = f2bf(o2 * scf);
    }
}

// ---------------------------------------------------------------------------
// V transpose: qkv v-slice [b][l][kv][d] -> Vt[b][kv][d][L]
// ---------------------------------------------------------------------------
__global__ __launch_bounds__(256) void transpose_v(const bf16* __restrict__ qkv,
                                                   bf16* __restrict__ Vt) {
    const int bk = blockIdx.x;
    const int l0 = blockIdx.y * 32;
    const int d0 = blockIdx.z * 32;
    const int b = bk >> 2, kv = bk & 3;
    __shared__ __align__(16) bf16 tile[32][40];
    const int t = threadIdx.x;
    {
        const int i = t >> 3, j4 = (t & 7) * 4;
        *reinterpret_cast<uint2*>(&tile[i][j4]) =
            *reinterpret_cast<const uint2*>(
                &qkv[(size_t)(b * 2048 + l0 + i) * 3072 + 2560 + kv * 128 + d0 + j4]);
    }
    __syncthreads();
    {
        const int j = t >> 3, i4 = (t & 7) * 4;
        alignas(8) bf16 v4[4];
#pragma unroll
        for (int u = 0; u < 4; ++u) v4[u] = tile[i4 + u][j];
        *reinterpret_cast<uint2*>(&Vt[((size_t)bk * 128 + d0 + j) * 2048 + l0 + i4]) =
            *reinterpret_cast<uint2*>(v4);
    }
}

// ---------------------------------------------------------------------------
// Causal GQA flash attention. K/V staged in LDS in MFMA-fragment order
// (conflict-free ds_read_b128 by construction). Double-buffered, KVB=32.
// Block = (b, h, 64 q-rows); 4 waves x 16 q-rows. LPT: qt descending.
// ---------------------------------------------------------------------------
__global__ __launch_bounds__(256, 4) void attn_fwd(const bf16* __restrict__ Q,
                                                   const bf16* __restrict__ Kb,
                                                   const bf16* __restrict__ Vt,
                                                   const float* __restrict__ maddf,
                                                   bf16* __restrict__ O) {
    // XCD-chunked swizzle: groups of 128 consecutive bids share one KV set.
    const int bid = (blockIdx.x & 7) * 128 + (blockIdx.x >> 3);
    const int qt = 31 - (bid & 31);  // longest blocks dispatch first
    const int h = (bid >> 5) & 15;
    const int b = bid >> 9;
    const int wave = threadIdx.x >> 6;
    const int lane = threadIdx.x & 63;
    const int fr = lane & 15, fg = lane >> 4;
    const int q0 = qt * 64 + wave * 16;
    const int hk = h >> 2;
    // fragment-order chunks: K[st*4+ks][lane][8], V[n][lane][8]
    __shared__ __align__(16) bf16 Ks[2][4096];
    __shared__ __align__(16) bf16 Vs[2][4096];
    __shared__ __align__(16) bf16 P[4][16][40];
    const bf16* qp = Q + (size_t)(b * 16 + h) * 2048 * 128;
    const bf16* kp = Kb + (size_t)(b * 4 + hk) * 2048 * 128;
    const bf16* vp = Vt + (size_t)(b * 4 + hk) * 128 * 2048;
    const float* mp = maddf + b * 2048;

    bf16x8 qf[4];
#pragma unroll
    for (int ks = 0; ks < 4; ++ks)
        qf[ks] = *reinterpret_cast<const bf16x8*>(
            &qp[(size_t)(q0 + fr) * 128 + ks * 32 + fg * 8]);

    f32x4 acc[8] = {};
    float mrow[4] = {-1e30f, -1e30f, -1e30f, -1e30f};
    float lrow[4] = {0.f, 0.f, 0.f, 0.f};
    const float SCALE = 0.08838834764831845f;  // 1/sqrt(128)
    const int nkv = 2 * qt + 2;

    // staging: thread (wave,lane) fills chunks wave and wave+4 of K and V.
    const int c0 = wave, c1 = wave + 4;
    const int krow0 = lane & 15;            // st=0 rows
    const int krow1 = 16 + (lane & 15);     // st=1 rows
    const int kcol = wave * 32 + (lane >> 4) * 8;
    const int vrow0 = wave * 16 + (lane & 15);
    const int vrow1 = vrow0 + 64;
    const int vcol = (lane >> 4) * 8;

#define STAGE_KV(buf, kv0)                                                     \
    do {                                                                       \
        gload16(&kp[(size_t)((kv0) + krow0) * 128 + kcol], &Ks[buf][c0 * 512]);\
        gload16(&kp[(size_t)((kv0) + krow1) * 128 + kcol], &Ks[buf][c1 * 512]);\
        gload16(&vp[(size_t)vrow0 * 2048 + (kv0) + vcol], &Vs[buf][c0 * 512]); \
        gload16(&vp[(size_t)vrow1 * 2048 + (kv0) + vcol], &Vs[buf][c1 * 512]); \
    } while (0)

    STAGE_KV(0, 0);
    __syncthreads();
    int cur = 0;

    for (int t = 0; t < nkv; ++t) {
        const int kv0 = t * 32;
        if (t + 1 < nkv) STAGE_KV(cur ^ 1, kv0 + 32);
        if (kv0 <= q0 + 15) {  // wave-uniform skip of fully-masked tiles
            f32x4 s[2] = {};
            __builtin_amdgcn_s_setprio(1);
#pragma unroll
            for (int st = 0; st < 2; ++st)
#pragma unroll
                for (int ks = 0; ks < 4; ++ks) {
                    bf16x8 kf = *reinterpret_cast<const bf16x8*>(
                        &Ks[cur][((st * 4 + ks) * 64 + lane) * 8]);
                    s[st] = MFMA16(qf[ks], kf, s[st]);
                }
            __builtin_amdgcn_s_setprio(0);
#pragma unroll
            for (int st = 0; st < 2; ++st) {
                const int col = kv0 + st * 16 + fr;
                const float madd = mp[col];
#pragma unroll
                for (int r = 0; r < 4; ++r) {
                    const int row = q0 + fg * 4 + r;
                    float v = s[st][r] * SCALE + madd;
                    if (col > row) v -= 10000.0f;
                    s[st][r] = v;
                }
            }
            float mx[4];
#pragma unroll
            for (int r = 0; r < 4; ++r) {
                float m0 = fmaxf(s[0][r], s[1][r]);
                m0 = fmaxf(m0, __shfl_xor(m0, 1));
                m0 = fmaxf(m0, __shfl_xor(m0, 2));
                m0 = fmaxf(m0, __shfl_xor(m0, 4));
                m0 = fmaxf(m0, __shfl_xor(m0, 8));
                mx[r] = m0;
            }
            const int ok = (mx[0] <= mrow[0] + 8.0f) & (mx[1] <= mrow[1] + 8.0f) &
                           (mx[2] <= mrow[2] + 8.0f) & (mx[3] <= mrow[3] + 8.0f);
            if (__all(ok)) {  // T13 defer-max: no rescale needed
#pragma unroll
                for (int r = 0; r < 4; ++r) {
                    float p0 = __expf(s[0][r] - mrow[r]);
                    float p1 = __expf(s[1][r] - mrow[r]);
                    s[0][r] = p0;
                    s[1][r] = p1;
                    float rs = p0 + p1;
                    rs += __shfl_xor(rs, 1);
                    rs += __shfl_xor(rs, 2);
                    rs += __shfl_xor(rs, 4);
                    rs += __shfl_xor(rs, 8);
                    lrow[r] += rs;
                }
            } else {
#pragma unroll
                for (int r = 0; r < 4; ++r) {
                    float nm = fmaxf(mrow[r], mx[r]);
                    float sc = __expf(mrow[r] - nm);
                    float p0 = __expf(s[0][r] - nm);
                    float p1 = __expf(s[1][r] - nm);
                    s[0][r] = p0;
                    s[1][r] = p1;
                    float rs = p0 + p1;
                    rs += __shfl_xor(rs, 1);
                    rs += __shfl_xor(rs, 2);
                    rs += __shfl_xor(rs, 4);
                    rs += __shfl_xor(rs, 8);
                    lrow[r] = lrow[r] * sc + rs;
                    mrow[r] = nm;
#pragma unroll
                    for (int n = 0; n < 8; ++n) acc[n][r] *= sc;
                }
            }
#pragma unroll
            for (int st = 0; st < 2; ++st)
#pragma unroll
                for (int r = 0; r < 4; ++r)
                    P[wave][fg * 4 + r][st * 16 + fr] = f2bf(s[st][r]);
            bf16x8 pf = *reinterpret_cast<const bf16x8*>(&P[wave][fr][fg * 8]);
            __builtin_amdgcn_s_setprio(1);
#pragma unroll
            for (int n = 0; n < 8; ++n) {
                bf16x8 vf = *reinterpret_cast<const bf16x8*>(
                    &Vs[cur][(n * 64 + lane) * 8]);
                acc[n] = MFMA16(pf, vf, acc[n]);
            }
            __builtin_amdgcn_s_setprio(0);
        }
        __syncthreads();
        cur ^= 1;
    }
#undef STAGE_KV

    float inv[4];
#pragma unroll
    for (int r = 0; r < 4; ++r) inv[r] = 1.0f / lrow[r];
#pragma unroll
    for (int n = 0; n < 8; ++n) {
#pragma unroll
        for (int r = 0; r < 4; ++r) {
            const float v = acc[n][r] * inv[r];
            O[(size_t)(b * 2048 + q0 + fg * 4 + r) * 2048 + h * 128 + n * 16 + fr] =
                f2bf(v);
        }
    }
}

// ---------------------------------------------------------------------------
extern "C" void kernel_launch(void* const* d_in, const int* in_sizes, int n_in,
                              void* d_out, int out_size, void* d_ws, size_t ws_size,
                              hipStream_t stream) {
    const float* x = (const float*)d_in[0];
    const float* cosb = (const float*)d_in[1];
    const float* sinb = (const float*)d_in[2];
    const int* mask = (const int*)d_in[3];
    const float* Wq = (const float*)d_in[4];
    const float* Wk = (const float*)d_in[5];
    const float* Wv = (const float*)d_in[6];
    const float* Wo = (const float*)d_in[7];
    float* out = (float*)d_out;

    char* p = (char*)d_ws;
    bf16* wqkv_t = (bf16*)p; p += (size_t)3072 * 2048 * 2;
    bf16* wo_t  = (bf16*)p; p += (size_t)2048 * 2048 * 2;
    bf16* x_bf  = (bf16*)p; p += (size_t)4096 * 2048 * 2;
    bf16* qkv_bf = (bf16*)p; p += (size_t)4096 * 3072 * 2;
    bf16* q_bf  = (bf16*)p; p += (size_t)2 * 16 * 2048 * 128 * 2;
    bf16* k_bf  = (bf16*)p; p += (size_t)2 * 4 * 2048 * 128 * 2;
    bf16* v_t   = (bf16*)p; p += (size_t)2 * 4 * 128 * 2048 * 2;
    float* maddf = (float*)p; p += (size_t)4096 * 4;
    bf16* o_bf  = x_bf;  // alias: x dead after GEMM1

    transpose_w<<<dim3(64, 64), 256, 0, stream>>>(Wq, wqkv_t, 2048);
    transpose_w<<<dim3(16, 64), 256, 0, stream>>>(Wk, wqkv_t + (size_t)2048 * 2048, 512);
    transpose_w<<<dim3(16, 64), 256, 0, stream>>>(Wv, wqkv_t + (size_t)2560 * 2048, 512);
    transpose_w<<<dim3(64, 64), 256, 0, stream>>>(Wo, wo_t, 2048);
    convert_x<<<4096, 256, 0, stream>>>(x, x_bf, 4096 * 2048 / 8);
    mask_to_f<<<16, 256, 0, stream>>>(mask, maddf, 4096);
    gemm_bt<bf16><<<dim3(24, 32), 256, 0, stream>>>(x_bf, wqkv_t, qkv_bf, 4096, 3072, 2048);
    rope_rms<<<4096, 256, 0, stream>>>(qkv_bf, cosb, sinb, q_bf, k_bf);
    transpose_v<<<dim3(8, 64, 4), 256, 0, stream>>>(qkv_bf, v_t);
    attn_fwd<<<1024, 256, 0, stream>>>(q_bf, k_bf, v_t, maddf, o_bf);
    gemm_bt<float><<<dim3(16, 32), 256, 0, stream>>>(o_bf, wo_t, out, 4096, 2048, 2048);
}

// Round 4
// 439.340 us; speedup vs baseline: 1.1868x; 1.1868x over previous
//
#include <hip/hip_runtime.h>
#include <hip/hip_bf16.h>

using bf16 = __hip_bfloat16;
using bf16x8 = __attribute__((ext_vector_type(8))) short;
using f32x4 = __attribute__((ext_vector_type(4))) float;

#define MFMA16(a, b, c) __builtin_amdgcn_mfma_f32_16x16x32_bf16((a), (b), (c), 0, 0, 0)

static __device__ __forceinline__ float bf2f(bf16 v) { return __bfloat162float(v); }
static __device__ __forceinline__ bf16 f2bf(float v) { return __float2bfloat16(v); }

typedef const __attribute__((address_space(1))) void* gptr_t;
typedef __attribute__((address_space(3))) void* lptr_t;
static __device__ __forceinline__ void gload16(const void* g, void* l) {
    __builtin_amdgcn_global_load_lds((gptr_t)g, (lptr_t)l, 16, 0, 0);
}

// ---------------------------------------------------------------------------
// Weight transpose + f32->bf16: W[K=2048][N] -> Wt[N][2048]
// ---------------------------------------------------------------------------
__global__ __launch_bounds__(256) void transpose_w(const float* __restrict__ W,
                                                   bf16* __restrict__ Wt, int N) {
    const int n0 = blockIdx.x * 32;
    const int k0 = blockIdx.y * 32;
    __shared__ __align__(16) float tile[32][36];
    const int t = threadIdx.x;
    {
        const int i = t >> 3, j4 = (t & 7) * 4;
        *reinterpret_cast<float4*>(&tile[i][j4]) =
            *reinterpret_cast<const float4*>(&W[(size_t)(k0 + i) * N + n0 + j4]);
    }
    __syncthreads();
    {
        const int j = t >> 3, i4 = (t & 7) * 4;
        alignas(8) bf16 v4[4];
#pragma unroll
        for (int u = 0; u < 4; ++u) v4[u] = f2bf(tile[i4 + u][j]);
        *reinterpret_cast<uint2*>(&Wt[(size_t)(n0 + j) * 2048 + k0 + i4]) =
            *reinterpret_cast<uint2*>(v4);
    }
}

// ---------------------------------------------------------------------------
// x f32 -> bf16 (vectorized 8/thread)
// ---------------------------------------------------------------------------
__global__ __launch_bounds__(256) void convert_x(const float* __restrict__ X,
                                                 bf16* __restrict__ Xb, int n8) {
    int idx = blockIdx.x * 256 + threadIdx.x;
    if (idx >= n8) return;
    const float4 a = reinterpret_cast<const float4*>(X)[idx * 2];
    const float4 c = reinterpret_cast<const float4*>(X)[idx * 2 + 1];
    alignas(16) bf16 v8[8];
    v8[0] = f2bf(a.x); v8[1] = f2bf(a.y); v8[2] = f2bf(a.z); v8[3] = f2bf(a.w);
    v8[4] = f2bf(c.x); v8[5] = f2bf(c.y); v8[6] = f2bf(c.z); v8[7] = f2bf(c.w);
    reinterpret_cast<int4*>(Xb)[idx] = *reinterpret_cast<int4*>(v8);
}

// ---------------------------------------------------------------------------
// mask -> additive float bias: maddf[i] = -10000 * (1 - mask[i])
// ---------------------------------------------------------------------------
__global__ __launch_bounds__(256) void mask_to_f(const int* __restrict__ m,
                                                 float* __restrict__ f, int n) {
    int i = blockIdx.x * 256 + threadIdx.x;
    if (i < n) f[i] = -10000.0f * (float)(1 - m[i]);
}

// ---------------------------------------------------------------------------
// GEMM (m97 structure): C[M][N] = A[M][K](bf16) @ Bt[N][K](bf16)^T, f32 acc.
// ---------------------------------------------------------------------------
template <typename OUT_T>
__global__ __launch_bounds__(256) void gemm_bt(const bf16* __restrict__ A,
                                               const bf16* __restrict__ Bt,
                                               OUT_T* __restrict__ C,
                                               int M, int N, int K) {
    __shared__ __align__(16) bf16 As[128 * 32];
    __shared__ __align__(16) bf16 Bs[128 * 32];
    const int t = threadIdx.x;
    const int lane = t & 63;
    const int wave = t >> 6;
    const int m0 = blockIdx.y * 128;
    const int n0 = blockIdx.x * 128;
    const int wr = (wave >> 1) * 64;
    const int wc = (wave & 1) * 64;
    const int fr = lane & 15;
    const int fg = lane >> 4;
    f32x4 acc[4][4] = {};
    const int g0 = wave * 2 * 64 + lane;
    const int g1 = g0 + 64;
    const int r0 = g0 >> 2, c0 = (g0 & 3) * 8;
    const int r1 = g1 >> 2, c1 = (g1 & 3) * 8;
    for (int k0 = 0; k0 < K; k0 += 32) {
        __syncthreads();
        gload16(&A[(size_t)(m0 + r0) * K + k0 + c0], &As[(size_t)g0 * 8 - lane * 8]);
        gload16(&A[(size_t)(m0 + r1) * K + k0 + c1], &As[(size_t)g1 * 8 - lane * 8]);
        gload16(&Bt[(size_t)(n0 + r0) * K + k0 + c0], &Bs[(size_t)g0 * 8 - lane * 8]);
        gload16(&Bt[(size_t)(n0 + r1) * K + k0 + c1], &Bs[(size_t)g1 * 8 - lane * 8]);
        __syncthreads();
        bf16x8 af[4], bfv[4];
#pragma unroll
        for (int m = 0; m < 4; ++m)
            af[m] = *reinterpret_cast<const bf16x8*>(&As[(wr + m * 16 + fr) * 32 + fg * 8]);
#pragma unroll
        for (int n = 0; n < 4; ++n)
            bfv[n] = *reinterpret_cast<const bf16x8*>(&Bs[(wc + n * 16 + fr) * 32 + fg * 8]);
#pragma unroll
        for (int m = 0; m < 4; ++m)
#pragma unroll
            for (int n = 0; n < 4; ++n)
                acc[m][n] = MFMA16(af[m], bfv[n], acc[m][n]);
    }
#pragma unroll
    for (int m = 0; m < 4; ++m) {
#pragma unroll
        for (int r = 0; r < 4; ++r) {
            const int grow = m0 + wr + m * 16 + fg * 4 + r;
#pragma unroll
            for (int n = 0; n < 4; ++n) {
                const int gcol = n0 + wc + n * 16 + fr;
                const float v = acc[m][n][r];
                if constexpr (sizeof(OUT_T) == 2)
                    C[(size_t)grow * N + gcol] = f2bf(v);
                else
                    C[(size_t)grow * N + gcol] = v;
            }
        }
    }
}

// ---------------------------------------------------------------------------
// RoPE + QK-RMS. qkv[4096][3072] bf16 row-major (q | k | v).
// ---------------------------------------------------------------------------
__global__ __launch_bounds__(256) void rope_rms(const bf16* __restrict__ qkv,
                                                const float* __restrict__ cosb,
                                                const float* __restrict__ sinb,
                                                bf16* __restrict__ Qo,
                                                bf16* __restrict__ Ko) {
    const int row = blockIdx.x;  // b*2048 + l
    const int b = row >> 11, l = row & 2047;
    const int wave = threadIdx.x >> 6, lane = threadIdx.x & 63;
    const bf16* src = qkv + (size_t)row * 3072;
#pragma unroll
    for (int i = 0; i < 4; ++i) {
        const int hh = wave * 4 + i;
        float x1 = bf2f(src[hh * 128 + lane]);
        float x2 = bf2f(src[hh * 128 + 64 + lane]);
        size_t cs = ((size_t)row * 16 + hh) * 128 + lane;
        float c = cosb[cs], sn = sinb[cs];
        float o1 = x1 * c - x2 * sn;
        float o2 = x2 * c + x1 * sn;
        float ss = o1 * o1 + o2 * o2;
#pragma unroll
        for (int off = 32; off >= 1; off >>= 1) ss += __shfl_xor(ss, off);
        float scf = rsqrtf(ss * (1.0f / 128.0f) + 1e-6f);
        bf16* dst = Qo + ((size_t)(b * 16 + hh) * 2048 + l) * 128;
        dst[lane] = f2bf(o1 * scf);
        dst[64 + lane] = f2bf(o2 * scf);
    }
    {
        const int hv = wave;
        float x1 = bf2f(src[2048 + hv * 128 + lane]);
        float x2 = bf2f(src[2048 + hv * 128 + 64 + lane]);
        size_t cs = ((size_t)row * 16 + hv) * 128 + lane;
        float c = cosb[cs], sn = sinb[cs];
        float o1 = x1 * c - x2 * sn;
        float o2 = x2 * c + x1 * sn;
        float ss = o1 * o1 + o2 * o2;
#pragma unroll
        for (int off = 32; off >= 1; off >>= 1) ss += __shfl_xor(ss, off);
        float scf = rsqrtf(ss * (1.0f / 128.0f) + 1e-6f);
        bf16* dst = Ko + ((size_t)(b * 4 + hv) * 2048 + l) * 128;
        dst[lane] = f2bf(o1 * scf);
        dst[64 + lane] = f2bf(o2 * scf);
    }
}

// ---------------------------------------------------------------------------
// V transpose: qkv v-slice [b][l][kv][d] -> Vt[b][kv][d][L]
// ---------------------------------------------------------------------------
__global__ __launch_bounds__(256) void transpose_v(const bf16* __restrict__ qkv,
                                                   bf16* __restrict__ Vt) {
    const int bk = blockIdx.x;
    const int l0 = blockIdx.y * 32;
    const int d0 = blockIdx.z * 32;
    const int b = bk >> 2, kv = bk & 3;
    __shared__ __align__(16) bf16 tile[32][40];
    const int t = threadIdx.x;
    {
        const int i = t >> 3, j4 = (t & 7) * 4;
        *reinterpret_cast<uint2*>(&tile[i][j4]) =
            *reinterpret_cast<const uint2*>(
                &qkv[(size_t)(b * 2048 + l0 + i) * 3072 + 2560 + kv * 128 + d0 + j4]);
    }
    __syncthreads();
    {
        const int j = t >> 3, i4 = (t & 7) * 4;
        alignas(8) bf16 v4[4];
#pragma unroll
        for (int u = 0; u < 4; ++u) v4[u] = tile[i4 + u][j];
        *reinterpret_cast<uint2*>(&Vt[((size_t)bk * 128 + d0 + j) * 2048 + l0 + i4]) =
            *reinterpret_cast<uint2*>(v4);
    }
}

// ---------------------------------------------------------------------------
// Causal GQA flash attention, swapped QK^T (in-lane softmax reduction).
// K/V in LDS in MFMA-fragment order (conflict-free). Double-buffered, KVB=32.
// Block = (b, h, 64 q-rows); 4 waves x 16 q-rows. LPT: qt descending.
// Lane layout after mfma(K,Q): s[st][r] = S[k=kv0+st*16+fg*4+r][q=q0+fr].
// Running m/l: one scalar per lane (q-row fr), duplicated across fg.
// ---------------------------------------------------------------------------
__global__ __launch_bounds__(256, 4) void attn_fwd(const bf16* __restrict__ Q,
                                                   const bf16* __restrict__ Kb,
                                                   const bf16* __restrict__ Vt,
                                                   const float* __restrict__ maddf,
                                                   bf16* __restrict__ O) {
    const int bid = (blockIdx.x & 7) * 128 + (blockIdx.x >> 3);
    const int qt = 31 - (bid & 31);
    const int h = (bid >> 5) & 15;
    const int b = bid >> 9;
    const int wave = threadIdx.x >> 6;
    const int lane = threadIdx.x & 63;
    const int fr = lane & 15, fg = lane >> 4;
    const int q0 = qt * 64 + wave * 16;
    const int hk = h >> 2;
    __shared__ __align__(16) bf16 Ks[2][4096];
    __shared__ __align__(16) bf16 Vs[2][4096];
    __shared__ __align__(16) bf16 P[4][16][40];
    const bf16* qp = Q + (size_t)(b * 16 + h) * 2048 * 128;
    const bf16* kp = Kb + (size_t)(b * 4 + hk) * 2048 * 128;
    const bf16* vp = Vt + (size_t)(b * 4 + hk) * 128 * 2048;
    const float* mp = maddf + b * 2048;

    bf16x8 qf[4];
#pragma unroll
    for (int ks = 0; ks < 4; ++ks)
        qf[ks] = *reinterpret_cast<const bf16x8*>(
            &qp[(size_t)(q0 + fr) * 128 + ks * 32 + fg * 8]);

    f32x4 acc[8] = {};
    float mrow = -1e30f;  // running max for q-row (q0+fr)
    float lrow = 0.f;     // running denom for q-row (q0+fr)
    const float SCALE = 0.08838834764831845f;  // 1/sqrt(128)
    const int qrow = q0 + fr;
    const int nkv = 2 * qt + 2;

    const int c0 = wave, c1 = wave + 4;
    const int krow0 = lane & 15;
    const int krow1 = 16 + (lane & 15);
    const int kcol = wave * 32 + (lane >> 4) * 8;
    const int vrow0 = wave * 16 + (lane & 15);
    const int vrow1 = vrow0 + 64;
    const int vcol = (lane >> 4) * 8;

#define STAGE_KV(buf, kv0)                                                     \
    do {                                                                       \
        gload16(&kp[(size_t)((kv0) + krow0) * 128 + kcol], &Ks[buf][c0 * 512]);\
        gload16(&kp[(size_t)((kv0) + krow1) * 128 + kcol], &Ks[buf][c1 * 512]);\
        gload16(&vp[(size_t)vrow0 * 2048 + (kv0) + vcol], &Vs[buf][c0 * 512]); \
        gload16(&vp[(size_t)vrow1 * 2048 + (kv0) + vcol], &Vs[buf][c1 * 512]); \
    } while (0)

    STAGE_KV(0, 0);
    __syncthreads();
    int cur = 0;

    for (int t = 0; t < nkv; ++t) {
        const int kv0 = t * 32;
        if (t + 1 < nkv) STAGE_KV(cur ^ 1, kv0 + 32);
        if (kv0 <= q0 + 15) {
            f32x4 s[2] = {};
            __builtin_amdgcn_s_setprio(1);
#pragma unroll
            for (int st = 0; st < 2; ++st)
#pragma unroll
                for (int ks = 0; ks < 4; ++ks) {
                    bf16x8 kf = *reinterpret_cast<const bf16x8*>(
                        &Ks[cur][((st * 4 + ks) * 64 + lane) * 8]);
                    s[st] = MFMA16(kf, qf[ks], s[st]);  // swapped: S^T
                }
            __builtin_amdgcn_s_setprio(0);
            // scale + mask + causal (cols are in-lane now)
#pragma unroll
            for (int st = 0; st < 2; ++st) {
                const float4 mv =
                    *reinterpret_cast<const float4*>(&mp[kv0 + st * 16 + fg * 4]);
#pragma unroll
                for (int r = 0; r < 4; ++r) {
                    const int col = kv0 + st * 16 + fg * 4 + r;
                    float v = s[st][r] * SCALE + (&mv.x)[r];
                    if (col > qrow) v -= 10000.0f;
                    s[st][r] = v;
                }
            }
            // tile max over k: 7 in-lane + 2 shuffles
            float mx = fmaxf(fmaxf(fmaxf(s[0][0], s[0][1]), fmaxf(s[0][2], s[0][3])),
                             fmaxf(fmaxf(s[1][0], s[1][1]), fmaxf(s[1][2], s[1][3])));
            mx = fmaxf(mx, __shfl_xor(mx, 16));
            mx = fmaxf(mx, __shfl_xor(mx, 32));
            if (__all(mx <= mrow + 8.0f)) {  // T13 defer-max
                float rs = 0.f;
#pragma unroll
                for (int st = 0; st < 2; ++st)
#pragma unroll
                    for (int r = 0; r < 4; ++r) {
                        float pv = __expf(s[st][r] - mrow);
                        s[st][r] = pv;
                        rs += pv;
                    }
                rs += __shfl_xor(rs, 16);
                rs += __shfl_xor(rs, 32);
                lrow += rs;
            } else {
                const float nm = fmaxf(mrow, mx);
                const float sc = __expf(mrow - nm);
                float rs = 0.f;
#pragma unroll
                for (int st = 0; st < 2; ++st)
#pragma unroll
                    for (int r = 0; r < 4; ++r) {
                        float pv = __expf(s[st][r] - nm);
                        s[st][r] = pv;
                        rs += pv;
                    }
                rs += __shfl_xor(rs, 16);
                rs += __shfl_xor(rs, 32);
                lrow = lrow * sc + rs;
                mrow = nm;
                // rescale acc: row q0+fg*4+r needs sc held at lane fr'=fg*4+r
#pragma unroll
                for (int r = 0; r < 4; ++r) {
                    const float scr = __shfl(sc, fg * 20 + r);
#pragma unroll
                    for (int n = 0; n < 8; ++n) acc[n][r] *= scr;
                }
            }
            // P write (transposed): P[q=fr][k=st*16+fg*4+r]
#pragma unroll
            for (int st = 0; st < 2; ++st)
#pragma unroll
                for (int r = 0; r < 4; ++r)
                    P[wave][fr][st * 16 + fg * 4 + r] = f2bf(s[st][r]);
            bf16x8 pf = *reinterpret_cast<const bf16x8*>(&P[wave][fr][fg * 8]);
            __builtin_amdgcn_s_setprio(1);
#pragma unroll
            for (int n = 0; n < 8; ++n) {
                bf16x8 vf = *reinterpret_cast<const bf16x8*>(
                    &Vs[cur][(n * 64 + lane) * 8]);
                acc[n] = MFMA16(pf, vf, acc[n]);
            }
            __builtin_amdgcn_s_setprio(0);
        }
        __syncthreads();
        cur ^= 1;
    }
#undef STAGE_KV

    // 1/l for q-row q0+fg*4+r lives at lane fr'=fg*4+r
    float inv[4];
#pragma unroll
    for (int r = 0; r < 4; ++r) inv[r] = 1.0f / __shfl(lrow, fg * 20 + r);
#pragma unroll
    for (int n = 0; n < 8; ++n) {
#pragma unroll
        for (int r = 0; r < 4; ++r) {
            const float v = acc[n][r] * inv[r];
            O[(size_t)(b * 2048 + q0 + fg * 4 + r) * 2048 + h * 128 + n * 16 + fr] =
                f2bf(v);
        }
    }
}

// ---------------------------------------------------------------------------
extern "C" void kernel_launch(void* const* d_in, const int* in_sizes, int n_in,
                              void* d_out, int out_size, void* d_ws, size_t ws_size,
                              hipStream_t stream) {
    const float* x = (const float*)d_in[0];
    const float* cosb = (const float*)d_in[1];
    const float* sinb = (const float*)d_in[2];
    const int* mask = (const int*)d_in[3];
    const float* Wq = (const float*)d_in[4];
    const float* Wk = (const float*)d_in[5];
    const float* Wv = (const float*)d_in[6];
    const float* Wo = (const float*)d_in[7];
    float* out = (float*)d_out;

    char* p = (char*)d_ws;
    bf16* wqkv_t = (bf16*)p; p += (size_t)3072 * 2048 * 2;
    bf16* wo_t  = (bf16*)p; p += (size_t)2048 * 2048 * 2;
    bf16* x_bf  = (bf16*)p; p += (size_t)4096 * 2048 * 2;
    bf16* qkv_bf = (bf16*)p; p += (size_t)4096 * 3072 * 2;
    bf16* q_bf  = (bf16*)p; p += (size_t)2 * 16 * 2048 * 128 * 2;
    bf16* k_bf  = (bf16*)p; p += (size_t)2 * 4 * 2048 * 128 * 2;
    bf16* v_t   = (bf16*)p; p += (size_t)2 * 4 * 128 * 2048 * 2;
    float* maddf = (float*)p; p += (size_t)4096 * 4;
    bf16* o_bf  = x_bf;  // alias: x dead after GEMM1

    transpose_w<<<dim3(64, 64), 256, 0, stream>>>(Wq, wqkv_t, 2048);
    transpose_w<<<dim3(16, 64), 256, 0, stream>>>(Wk, wqkv_t + (size_t)2048 * 2048, 512);
    transpose_w<<<dim3(16, 64), 256, 0, stream>>>(Wv, wqkv_t + (size_t)2560 * 2048, 512);
    transpose_w<<<dim3(64, 64), 256, 0, stream>>>(Wo, wo_t, 2048);
    convert_x<<<4096, 256, 0, stream>>>(x, x_bf, 4096 * 2048 / 8);
    mask_to_f<<<16, 256, 0, stream>>>(mask, maddf, 4096);
    gemm_bt<bf16><<<dim3(24, 32), 256, 0, stream>>>(x_bf, wqkv_t, qkv_bf, 4096, 3072, 2048);
    rope_rms<<<4096, 256, 0, stream>>>(qkv_bf, cosb, sinb, q_bf, k_bf);
    transpose_v<<<dim3(8, 64, 4), 256, 0, stream>>>(qkv_bf, v_t);
    attn_fwd<<<1024, 256, 0, stream>>>(q_bf, k_bf, v_t, maddf, o_bf);
    gemm_bt<float><<<dim3(16, 32), 256, 0, stream>>>(o_bf, wo_t, out, 4096, 2048, 2048);
}